// Round 2
// baseline (24.529 us; speedup 1.0000x reference)
//
#include <hip/hip_runtime.h>

// Problem constants (from setup_inputs): B=4, H=512, W=512
#define B_   4
#define H_   512
#define W_   512
#define HW_  (H_ * W_)

#define NBLK 1024   // NBLK*NTHR == HW_ exactly: one thread per spatial position
#define NTHR 256

// Reference semantics (after resolving the (B,H,W) vs (B,1,H,W) broadcast,
// which produces a (B,B,HW,9) loss tensor):
//   c0[p]   = #{b : pred[b,0,p] >= pred[b,1,p]}          (argmax ties -> 0)
//   S[a,p]  = pred[a,0,p]*c0[p] - pred[a,1,p]*(B-c0[p])  (sum of unified over broadcast b)
//   w[a,p,k]= ign * fpe * dne   (gt-based masks, zero-padded neighborhood)
//   loss    = sum_{a,p,k} w * (B - gr*S[a,p])
//   result  = loss / max(sum ign, 1)
__global__ __launch_bounds__(NTHR) void elev_partial_kernel(
    const float* __restrict__ pred,   // (B,2,H,W)
    const float* __restrict__ hts,    // (B,1,H,W)
    const float* __restrict__ gt,     // (B,1,H,W)
    double* __restrict__ partial)     // (NBLK, 2)
{
    const int p = blockIdx.x * NTHR + threadIdx.x;   // spatial position in [0, HW_)
    const int i = p >> 9;          // / W_
    const int j = p & (W_ - 1);

    // Cross-batch argmax count at this spatial position
    float p0[B_], p1[B_];
    int c0 = 0;
    #pragma unroll
    for (int b = 0; b < B_; ++b) {
        p0[b] = pred[(size_t)b * 2 * HW_ + p];
        p1[b] = pred[(size_t)b * 2 * HW_ + HW_ + p];
        // idx==0 iff NOT (p1 > p0)  (jnp.argmax ties -> first index)
        c0 += (p1[b] > p0[b]) ? 0 : 1;
    }
    const float c0f = (float)c0;
    const float c1f = (float)(B_ - c0);

    float lacc = 0.0f;
    int   vcnt = 0;

    #pragma unroll
    for (int b = 0; b < B_; ++b) {
        const float S  = p0[b] * c0f - p1[b] * c1f;   // sum_b' unified[b, b', p]
        const float* hb = hts + (size_t)b * HW_;
        const float* gb = gt  + (size_t)b * HW_;
        const float hc = hb[p];

        #pragma unroll
        for (int di = -1; di <= 1; ++di) {
            #pragma unroll
            for (int dj = -1; dj <= 1; ++dj) {
                const int ni = i + di;
                const int nj = j + dj;
                const bool inb = ((unsigned)ni < H_) && ((unsigned)nj < W_);
                const float g  = inb ? gb[ni * W_ + nj] : 0.0f;   // zero pad
                const float hn = inb ? hb[ni * W_ + nj] : 0.0f;

                if (g != 255.0f) {   // ignore_mask
                    vcnt += 1;
                    const float gr = (g == 0.0f) ? -1.0f : 1.0f;  // 0->-1, 1->1
                    const float delta = hc - hn;
                    const float fpe = (g == 1.0f && delta > 0.0f) ? 0.0f : 1.0f;
                    const float dne = (g == 0.0f && delta < 0.0f) ? 0.0f : 1.0f;
                    // sum over broadcast batch axis of score: B - gr*S
                    lacc += fpe * dne * ((float)B_ - gr * S);
                }
            }
        }
    }

    double loss_acc  = (double)lacc;
    double valid_acc = (double)vcnt;

    // wave (64-lane) butterfly reduce, then LDS across the 4 waves
    for (int off = 32; off > 0; off >>= 1) {
        loss_acc  += __shfl_down(loss_acc,  off, 64);
        valid_acc += __shfl_down(valid_acc, off, 64);
    }
    __shared__ double s_l[NTHR / 64];
    __shared__ double s_v[NTHR / 64];
    const int wave = threadIdx.x >> 6;
    const int lane = threadIdx.x & 63;
    if (lane == 0) { s_l[wave] = loss_acc; s_v[wave] = valid_acc; }
    __syncthreads();
    if (threadIdx.x == 0) {
        double l = s_l[0], v = s_v[0];
        #pragma unroll
        for (int w = 1; w < NTHR / 64; ++w) { l += s_l[w]; v += s_v[w]; }
        partial[2 * (size_t)blockIdx.x + 0] = l;
        partial[2 * (size_t)blockIdx.x + 1] = v;
    }
}

// Kernel 2: single block folds the NBLK partials deterministically.
__global__ __launch_bounds__(1024) void elev_final_kernel(
    const double* __restrict__ partial, float* __restrict__ out)
{
    double l = 0.0, v = 0.0;
    for (int i = threadIdx.x; i < NBLK; i += 1024) {
        l += partial[2 * (size_t)i + 0];
        v += partial[2 * (size_t)i + 1];
    }
    for (int off = 32; off > 0; off >>= 1) {
        l += __shfl_down(l, off, 64);
        v += __shfl_down(v, off, 64);
    }
    __shared__ double s_l[16];
    __shared__ double s_v[16];
    const int wave = threadIdx.x >> 6;
    const int lane = threadIdx.x & 63;
    if (lane == 0) { s_l[wave] = l; s_v[wave] = v; }
    __syncthreads();
    if (threadIdx.x == 0) {
        double tl = s_l[0], tv = s_v[0];
        #pragma unroll
        for (int w = 1; w < 16; ++w) { tl += s_l[w]; tv += s_v[w]; }
        const double nv = tv > 1.0 ? tv : 1.0;
        out[0] = (float)(tl / nv);
    }
}

extern "C" void kernel_launch(void* const* d_in, const int* in_sizes, int n_in,
                              void* d_out, int out_size, void* d_ws, size_t ws_size,
                              hipStream_t stream) {
    const float* pred = (const float*)d_in[0];   // (4,2,512,512) f32
    const float* hts  = (const float*)d_in[1];   // (4,1,512,512) f32
    const float* gt   = (const float*)d_in[2];   // (4,1,512,512) f32
    float* out        = (float*)d_out;           // scalar f32
    double* partial   = (double*)d_ws;           // NBLK * 2 doubles = 16 KiB

    elev_partial_kernel<<<NBLK, NTHR, 0, stream>>>(pred, hts, gt, partial);
    elev_final_kernel<<<1, 1024, 0, stream>>>(partial, out);
}